// Round 1
// baseline (378.498 us; speedup 1.0000x reference)
//
#include <hip/hip_runtime.h>
#include <math.h>

#define BB 128
#define CC 512
#define HW 1024
#define EE 16
#define KK 2
#define INV_NOISE_STD 16.0f
#define TAU 1.0f
#define EPSV 1e-8f

__device__ __forceinline__ float wave_sum(float v) {
    #pragma unroll
    for (int off = 32; off > 0; off >>= 1) v += __shfl_down(v, off, 64);
    return v;
}

// Kernel A: pooled[p] = mean over 1024 contiguous floats. One wave per p.
__global__ void __launch_bounds__(256) pool_kernel(const float* __restrict__ x,
                                                   float* __restrict__ pooled) {
    int wave = (blockIdx.x * 256 + threadIdx.x) >> 6;   // global wave id = (b*C+c)
    int lane = threadIdx.x & 63;
    if (wave >= BB * CC) return;
    const float4* p = (const float4*)(x + (size_t)wave * HW);
    float s = 0.0f;
    #pragma unroll
    for (int j = 0; j < 4; ++j) {
        float4 v = p[lane + 64 * j];
        s += (v.x + v.y) + (v.z + v.w);
    }
    s = wave_sum(s);
    if (lane == 0) pooled[wave] = s * (1.0f / 1024.0f);
}

// Kernel B: logits[b,e] = dot(pooled[b,:], W_gate[e,:]). One block per b.
__global__ void __launch_bounds__(256) logits_kernel(const float* __restrict__ pooled,
                                                     const float* __restrict__ Wg,
                                                     float* __restrict__ logits) {
    __shared__ float prow[CC];
    int b = blockIdx.x;
    for (int c = threadIdx.x; c < CC; c += 256) prow[c] = pooled[b * CC + c];
    __syncthreads();
    int t = threadIdx.x;
    int e = t >> 4;      // 0..15
    int g = t & 15;      // 0..15
    float s = 0.0f;
    for (int c = g; c < CC; c += 16) s += prow[c] * Wg[e * CC + c];
    #pragma unroll
    for (int off = 8; off > 0; off >>= 1) s += __shfl_down(s, off, 16);
    if (g == 0) logits[b * EE + e] = s;
}

// Kernel C: all statistics + outputs. Single block, 128 threads (1 per batch row).
__global__ void __launch_bounds__(128) stats_kernel(const float* __restrict__ logits,
                                                    const float* __restrict__ complexity,
                                                    const float* __restrict__ noise,
                                                    float* __restrict__ out) {
    // out layout: gates[B*E] | idx[B*K] | vals[B*K] | aux[1]
    __shared__ float imp[EE];    // sum over b of softmax(logits)
    __shared__ float psum[EE];   // sum over b of p
    int t = threadIdx.x;
    int lane = t & 63;
    if (t < EE) { imp[t] = 0.0f; psum[t] = 0.0f; }
    __syncthreads();

    int b = t;
    float lg[EE], nlg[EE];
    #pragma unroll
    for (int e = 0; e < EE; ++e) lg[e] = logits[b * EE + e];
    #pragma unroll
    for (int e = 0; e < EE; ++e) nlg[e] = lg[e] + noise[b * EE + e];

    // softmax(logits) -> importance accumulation
    float mx = lg[0];
    #pragma unroll
    for (int e = 1; e < EE; ++e) mx = fmaxf(mx, lg[e]);
    float sm[EE]; float se = 0.0f;
    #pragma unroll
    for (int e = 0; e < EE; ++e) { sm[e] = expf(lg[e] - mx); se += sm[e]; }
    float inv_se = 1.0f / se;
    #pragma unroll
    for (int e = 0; e < EE; ++e) {
        float ws = wave_sum(sm[e] * inv_se);
        if (lane == 0) atomicAdd(&imp[e], ws);
    }

    // softmax(noisy logits) -> gating scores; top-2 (jax tie-break: lowest index)
    float mxn = nlg[0];
    #pragma unroll
    for (int e = 1; e < EE; ++e) mxn = fmaxf(mxn, nlg[e]);
    float gsc[EE]; float sen = 0.0f;
    #pragma unroll
    for (int e = 0; e < EE; ++e) { gsc[e] = expf(nlg[e] - mxn); sen += gsc[e]; }
    float inv_sen = 1.0f / sen;
    #pragma unroll
    for (int e = 0; e < EE; ++e) gsc[e] *= inv_sen;

    int i1 = 0;
    #pragma unroll
    for (int e = 1; e < EE; ++e) if (nlg[e] > nlg[i1]) i1 = e;
    int i2 = (i1 == 0) ? 1 : 0;
    #pragma unroll
    for (int e = 0; e < EE; ++e) if (e != i1 && e != i2 && nlg[e] > nlg[i2]) i2 = e;
    float thr = nlg[i2];
    float v1 = gsc[i1], v2 = gsc[i2];

    // load-balance probability p[e] = 0.5*erfc((thr - lg[e]) * 16 / sqrt(2))
    #pragma unroll
    for (int e = 0; e < EE; ++e) {
        float z = (thr - lg[e]) * INV_NOISE_STD;
        float p = 0.5f * erfcf(z * 0.70710678118654752f);
        float ws = wave_sum(p);
        if (lane == 0) atomicAdd(&psum[e], ws);
    }

    // dense gates + top-k outputs
    #pragma unroll
    for (int e = 0; e < EE; ++e)
        out[b * EE + e] = (e == i1) ? v1 : ((e == i2) ? v2 : 0.0f);
    out[BB * EE + b * KK + 0] = (float)i1;
    out[BB * EE + b * KK + 1] = (float)i2;
    out[BB * EE + BB * KK + b * KK + 0] = v1;
    out[BB * EE + BB * KK + b * KK + 1] = v2;

    __syncthreads();
    if (t == 0) {
        // loss_imp: importance = imp * complexity * TAU; (std_ddof1 / (mean+eps))^2
        float im[EE]; float mean1 = 0.0f;
        #pragma unroll
        for (int e = 0; e < EE; ++e) { im[e] = imp[e] * complexity[e] * TAU; mean1 += im[e]; }
        mean1 *= (1.0f / EE);
        float var1 = 0.0f;
        #pragma unroll
        for (int e = 0; e < EE; ++e) { float d = im[e] - mean1; var1 += d * d; }
        var1 *= (1.0f / (EE - 1));
        float li = var1 / ((mean1 + EPSV) * (mean1 + EPSV));

        float pm[EE]; float mean2 = 0.0f;
        #pragma unroll
        for (int e = 0; e < EE; ++e) { pm[e] = psum[e] * (1.0f / BB); mean2 += pm[e]; }
        mean2 *= (1.0f / EE);
        float var2 = 0.0f;
        #pragma unroll
        for (int e = 0; e < EE; ++e) { float d = pm[e] - mean2; var2 += d * d; }
        var2 *= (1.0f / (EE - 1));
        float ll = var2 / ((mean2 + EPSV) * (mean2 + EPSV));

        out[BB * EE + 2 * BB * KK] = 0.5f * li + 0.5f * ll;
    }
}

extern "C" void kernel_launch(void* const* d_in, const int* in_sizes, int n_in,
                              void* d_out, int out_size, void* d_ws, size_t ws_size,
                              hipStream_t stream) {
    const float* x     = (const float*)d_in[0];   // [128,512,32,32]
    const float* Wg    = (const float*)d_in[1];   // [16,512]
    const float* comp  = (const float*)d_in[2];   // [16]  (already normalized by max)
    const float* noise = (const float*)d_in[3];   // [128,16]
    float* out = (float*)d_out;

    float* pooled = (float*)d_ws;          // B*C = 65536 floats
    float* logits = pooled + BB * CC;      // B*E = 2048 floats

    pool_kernel<<<(BB * CC) / 4, 256, 0, stream>>>(x, pooled);
    logits_kernel<<<BB, 256, 0, stream>>>(pooled, Wg, logits);
    stats_kernel<<<1, 128, 0, stream>>>(logits, comp, noise, out);
}